// Round 2
// baseline (5235.857 us; speedup 1.0000x reference)
//
#include <hip/hip_runtime.h>
#include <math.h>

#define T_ 256
#define B_ 8
#define S_ 512
#define E_ 1024
#define FF_ 4096
#define V_ 32000
#define LN_EPSF 1e-5f

// ---------------- block reduction helpers (256 threads = 4 waves) ----------
__device__ __forceinline__ float blkSum(float v, float* sh) {
#pragma unroll
  for (int o = 32; o > 0; o >>= 1) v += __shfl_down(v, o, 64);
  if ((threadIdx.x & 63) == 0) sh[threadIdx.x >> 6] = v;
  __syncthreads();
  float r = sh[0] + sh[1] + sh[2] + sh[3];
  __syncthreads();
  return r;
}
__device__ __forceinline__ float blkMax(float v, float* sh) {
#pragma unroll
  for (int o = 32; o > 0; o >>= 1) v = fmaxf(v, __shfl_down(v, o, 64));
  if ((threadIdx.x & 63) == 0) sh[threadIdx.x >> 6] = v;
  __syncthreads();
  float r = fmaxf(fmaxf(sh[0], sh[1]), fmaxf(sh[2], sh[3]));
  __syncthreads();
  return r;
}

// ---------------- C = act((A @ B^T + bias) * scale + sbias[z]) --------------
// A: M x K (row stride lda), B: N x K (row stride ldb)  -- both K-contiguous.
// 64x64 tile, BK=16, 256 threads, 4x4 per thread.
__global__ __launch_bounds__(256) void gemm_ant(
    const float* __restrict__ A, const float* __restrict__ Bm,
    const float* __restrict__ bias, const float* __restrict__ sbias,
    float* __restrict__ C, int M, int N, int K,
    int lda, int ldb, int ldc, long aB, long bB, long cB,
    float scale, int relu)
{
  const int bz = blockIdx.z;
  A  += (long)bz * aB;
  Bm += (long)bz * bB;
  C  += (long)bz * cB;
  const float sb = sbias ? sbias[bz] : 0.0f;

  __shared__ float As[64][17];
  __shared__ float Bs[64][17];
  const int tx = threadIdx.x & 15, ty = threadIdx.x >> 4;
  const int row0 = blockIdx.y * 64, col0 = blockIdx.x * 64;

  float acc[4][4] = {};
  for (int k0 = 0; k0 < K; k0 += 16) {
#pragma unroll
    for (int i = 0; i < 4; ++i) {
      int idx = threadIdx.x + 256 * i;
      int r = idx >> 4, c = idx & 15;
      As[r][c] = A[(long)(row0 + r) * lda + k0 + c];
      Bs[r][c] = Bm[(long)(col0 + r) * ldb + k0 + c];
    }
    __syncthreads();
#pragma unroll
    for (int kk = 0; kk < 16; ++kk) {
      float av[4], bv[4];
#pragma unroll
      for (int i = 0; i < 4; ++i) av[i] = As[ty * 4 + i][kk];
#pragma unroll
      for (int j = 0; j < 4; ++j) bv[j] = Bs[tx * 4 + j][kk];
#pragma unroll
      for (int i = 0; i < 4; ++i)
#pragma unroll
        for (int j = 0; j < 4; ++j)
          acc[i][j] = fmaf(av[i], bv[j], acc[i][j]);
    }
    __syncthreads();
  }
#pragma unroll
  for (int i = 0; i < 4; ++i)
#pragma unroll
    for (int j = 0; j < 4; ++j) {
      int m = row0 + ty * 4 + i, n = col0 + tx * 4 + j;
      float v = acc[i][j] + (bias ? bias[n] : 0.0f);
      v = v * scale + sb;
      if (relu) v = fmaxf(v, 0.0f);
      C[(long)m * ldc + n] = v;
    }
}

// ---------------- C = A @ B (B not transposed) ------------------------------
// A: M x K (lda), B: K x N (ldb, n-contiguous rows). 64x64 tile, BK=16.
__global__ __launch_bounds__(256) void gemm_ab(
    const float* __restrict__ A, const float* __restrict__ Bm,
    float* __restrict__ C, int M, int N, int K,
    int lda, int ldb, int ldc, long aB, long bB, long cB)
{
  const int bz = blockIdx.z;
  A  += (long)bz * aB;
  Bm += (long)bz * bB;
  C  += (long)bz * cB;

  __shared__ float As[64][17];
  __shared__ float Bs[16][65];
  const int tx = threadIdx.x & 15, ty = threadIdx.x >> 4;
  const int row0 = blockIdx.y * 64, col0 = blockIdx.x * 64;

  float acc[4][4] = {};
  for (int k0 = 0; k0 < K; k0 += 16) {
#pragma unroll
    for (int i = 0; i < 4; ++i) {
      int idx = threadIdx.x + 256 * i;
      int r = idx >> 4, c = idx & 15;
      As[r][c] = A[(long)(row0 + r) * lda + k0 + c];
      int rb = idx >> 6, cb = idx & 63;
      Bs[rb][cb] = Bm[(long)(k0 + rb) * ldb + col0 + cb];
    }
    __syncthreads();
#pragma unroll
    for (int kk = 0; kk < 16; ++kk) {
      float av[4], bv[4];
#pragma unroll
      for (int i = 0; i < 4; ++i) av[i] = As[ty * 4 + i][kk];
#pragma unroll
      for (int j = 0; j < 4; ++j) bv[j] = Bs[kk][tx * 4 + j];
#pragma unroll
      for (int i = 0; i < 4; ++i)
#pragma unroll
        for (int j = 0; j < 4; ++j)
          acc[i][j] = fmaf(av[i], bv[j], acc[i][j]);
    }
    __syncthreads();
  }
#pragma unroll
  for (int i = 0; i < 4; ++i)
#pragma unroll
    for (int j = 0; j < 4; ++j)
      C[(long)(row0 + ty * 4 + i) * ldc + col0 + tx * 4 + j] = acc[i][j];
}

// ---------------- masked softmax over s for w[b,t,:] -------------------------
// mem_mask is bool in the reference; harness passes integer inputs as int32.
__global__ __launch_bounds__(256) void attn_softmax(
    float* __restrict__ w, const int* __restrict__ mask)
{
  __shared__ float sh[4];
  const int blk = blockIdx.x;          // b*T + t
  const int b = blk / T_;
  float* row = w + (long)blk * S_;
  const int s0 = threadIdx.x, s1 = threadIdx.x + 256;
  const bool k0 = mask[s0 * B_ + b] != 0;
  const bool k1 = mask[s1 * B_ + b] != 0;
  float x0 = k0 ? row[s0] : -INFINITY;
  float x1 = k1 ? row[s1] : -INFINITY;
  float m = blkMax(fmaxf(x0, x1), sh);
  float e0 = k0 ? expf(x0 - m) : 0.0f;
  float e1 = k1 ? expf(x1 - m) : 0.0f;
  float sum = blkSum(e0 + e1, sh);
  float inv = sum > 0.0f ? 1.0f / sum : 0.0f;
  row[s0] = e0 * inv;
  row[s1] = e1 * inv;
}

// ---------------- gates (softmax2 of [outs, LN(attn)] @ div_w^T) + h1 -------
__global__ __launch_bounds__(256) void gates_h1(
    const float* __restrict__ outs, const float* __restrict__ attn,
    const float* __restrict__ aln_g, const float* __restrict__ aln_b,
    const float* __restrict__ div_w, const float* __restrict__ div_b,
    float* __restrict__ h1, float* __restrict__ gen, float* __restrict__ cpy)
{
  __shared__ float sh[4];
  const long base = (long)blockIdx.x * E_;
  float a[4], o[4];
  float sa = 0.f, sa2 = 0.f, shh = 0.f, sh2 = 0.f;
#pragma unroll
  for (int i = 0; i < 4; ++i) {
    int e = threadIdx.x + 256 * i;
    a[i] = attn[base + e];
    o[i] = outs[base + e];
    sa += a[i]; sa2 += a[i] * a[i];
    float t = o[i] + a[i];
    shh += t; sh2 += t * t;
  }
  sa  = blkSum(sa, sh);
  sa2 = blkSum(sa2, sh);
  shh = blkSum(shh, sh);
  sh2 = blkSum(sh2, sh);
  const float ma = sa / E_, va = sa2 / E_ - ma * ma;
  const float mh = shh / E_, vh = sh2 / E_ - mh * mh;
  const float ra = rsqrtf(va + LN_EPSF), rh = rsqrtf(vh + LN_EPSF);

  float z0 = 0.f, z1 = 0.f;
#pragma unroll
  for (int i = 0; i < 4; ++i) {
    int e = threadIdx.x + 256 * i;
    float g = aln_g[e], bb = aln_b[e];
    float an = (a[i] - ma) * ra * g + bb;            // LN(attn)
    float hv = (o[i] + a[i] - mh) * rh * g + bb;     // LN(outs+attn)
    h1[base + e] = hv;
    z0 += o[i] * div_w[e]          + an * div_w[E_ + e];
    z1 += o[i] * div_w[2 * E_ + e] + an * div_w[3 * E_ + e];
  }
  z0 = blkSum(z0, sh);
  z1 = blkSum(z1, sh);
  if (threadIdx.x == 0) {
    z0 += div_b[0]; z1 += div_b[1];
    float mm = fmaxf(z0, z1);
    float e0 = expf(z0 - mm), e1 = expf(z1 - mm);
    float inv = 1.0f / (e0 + e1);
    gen[blockIdx.x] = e0 * inv;
    cpy[blockIdx.x] = e1 * inv;
  }
}

// ---------------- in-place LayerNorm over last dim E -------------------------
__global__ __launch_bounds__(256) void ln_inplace(
    float* __restrict__ x, const float* __restrict__ g, const float* __restrict__ b)
{
  __shared__ float sh[4];
  const long base = (long)blockIdx.x * E_;
  float v[4];
  float s = 0.f, s2 = 0.f;
#pragma unroll
  for (int i = 0; i < 4; ++i) {
    v[i] = x[base + threadIdx.x + 256 * i];
    s += v[i]; s2 += v[i] * v[i];
  }
  s  = blkSum(s, sh);
  s2 = blkSum(s2, sh);
  const float m = s / E_, var = s2 / E_ - m * m;
  const float r = rsqrtf(var + LN_EPSF);
#pragma unroll
  for (int i = 0; i < 4; ++i) {
    int e = threadIdx.x + 256 * i;
    x[base + e] = (v[i] - m) * r * g[e] + b[e];
  }
}

// ---------------- per-row: softmax(V) * gen + scatter(copy) -----------------
__global__ __launch_bounds__(256) void final_scatter(
    float* __restrict__ out,              // (T*B, V): logits in, probs out
    const float* __restrict__ w,          // (B,T,S) post-softmax
    const float* __restrict__ gen, const float* __restrict__ cpy,
    const int* __restrict__ copy_seq)     // (S,B)
{
  __shared__ float sh[4];
  const int r = blockIdx.x;               // t*B + b
  const int t = r / B_, b = r % B_;
  float* row = out + (long)r * V_;

  float mx = -INFINITY;
  for (int v = threadIdx.x; v < V_; v += 256) mx = fmaxf(mx, row[v]);
  mx = blkMax(mx, sh);

  float s = 0.f;
  for (int v = threadIdx.x; v < V_; v += 256) s += expf(row[v] - mx);
  s = blkSum(s, sh);

  const float scale = gen[r] / s;
  for (int v = threadIdx.x; v < V_; v += 256) row[v] = expf(row[v] - mx) * scale;
  __syncthreads();

  const float cg = cpy[r];
  const float* wrow = w + ((long)b * T_ + t) * S_;
  for (int sdx = threadIdx.x; sdx < S_; sdx += 256)
    atomicAdd(&row[copy_seq[sdx * B_ + b]], cg * wrow[sdx]);
}

// ---------------- elementwise log(p + 1e-12), separate dispatch -------------
// (kernel boundary guarantees the atomics above are visible; no L1 staleness)
__global__ __launch_bounds__(256) void log_k(float* __restrict__ out, long n)
{
  long i = (long)blockIdx.x * 256 + threadIdx.x;
  long stride = (long)gridDim.x * 256;
  for (; i < n; i += stride) out[i] = logf(out[i] + 1e-12f);
}

// ---------------- launch -----------------------------------------------------
extern "C" void kernel_launch(void* const* d_in, const int* in_sizes, int n_in,
                              void* d_out, int out_size, void* d_ws, size_t ws_size,
                              hipStream_t stream) {
  (void)in_sizes; (void)n_in; (void)out_size; (void)ws_size;
  const float* outs     = (const float*)d_in[0];
  const float* mem      = (const float*)d_in[1];
  const float* mem_bias = (const float*)d_in[2];
  const float* in_w     = (const float*)d_in[3];
  const float* in_b     = (const float*)d_in[4];
  const float* ow       = (const float*)d_in[5];
  const float* ob       = (const float*)d_in[6];
  const float* aln_g    = (const float*)d_in[7];
  const float* aln_b    = (const float*)d_in[8];
  const float* div_w    = (const float*)d_in[9];
  const float* div_b    = (const float*)d_in[10];
  const float* fc1_w    = (const float*)d_in[11];
  const float* fc1_b    = (const float*)d_in[12];
  const float* fc2_w    = (const float*)d_in[13];
  const float* fc2_b    = (const float*)d_in[14];
  const float* ffn_g    = (const float*)d_in[15];
  const float* ffn_b    = (const float*)d_in[16];
  const float* vocab_w  = (const float*)d_in[17];
  const int*   mask     = (const int*)d_in[18];
  const int*   copy_seq = (const int*)d_in[19];
  float* out = (float*)d_out;
  float* ws  = (float*)d_ws;

  // workspace layout (floats); ctx reuses q, h1 reuses v, h2 reuses k,
  // FFN intermediate lives in d_out (dead before logits are written)
  float* k    = ws;                   // 4096*1024
  float* v    = ws + 4194304;         // 4096*1024
  float* q    = ws + 8388608;         // 2048*1024
  float* w    = ws + 10485760;        // 8*256*512
  float* attn = ws + 11534336;        // 2048*1024
  float* gen  = ws + 13631488;        // 2048
  float* cpy  = gen + 2048;           // 2048
  float* ctx  = q;
  float* h1   = v;
  float* h2   = k;
  float* mid  = out;

  dim3 blk(256);
  // q = (outs @ Wq^T + bq) * E^-0.5
  gemm_ant<<<dim3(16, 32, 1), blk, 0, stream>>>(outs, in_w, in_b, nullptr, q,
      2048, 1024, 1024, 1024, 1024, 1024, 0, 0, 0, 0.03125f, 0);
  // k = mem @ Wk^T + bk
  gemm_ant<<<dim3(16, 64, 1), blk, 0, stream>>>(mem, in_w + E_ * E_, in_b + E_, nullptr, k,
      4096, 1024, 1024, 1024, 1024, 1024, 0, 0, 0, 1.0f, 0);
  // v = mem @ Wv^T + bv
  gemm_ant<<<dim3(16, 64, 1), blk, 0, stream>>>(mem, in_w + 2 * E_ * E_, in_b + 2 * E_, nullptr, v,
      4096, 1024, 1024, 1024, 1024, 1024, 0, 0, 0, 1.0f, 0);
  // w[b,t,s] = q[t,b,:] . k[s,b,:] + mem_bias[b]   (batched over b)
  gemm_ant<<<dim3(8, 4, 8), blk, 0, stream>>>(q, k, nullptr, mem_bias, w,
      256, 512, 1024, B_ * E_, B_ * E_, S_, E_, E_, (long)T_ * S_, 1.0f, 0);
  attn_softmax<<<dim3(B_ * T_), blk, 0, stream>>>(w, mask);
  // ctx[t,b,:] = sum_s w[b,t,s] * v[s,b,:]
  gemm_ab<<<dim3(16, 4, 8), blk, 0, stream>>>(w, v, ctx,
      256, 1024, 512, S_, B_ * E_, B_ * E_, (long)T_ * S_, E_, E_);
  // attn = ctx @ Wo^T + bo
  gemm_ant<<<dim3(16, 32, 1), blk, 0, stream>>>(ctx, ow, ob, nullptr, attn,
      2048, 1024, 1024, 1024, 1024, 1024, 0, 0, 0, 1.0f, 0);
  // gates + h1 = LN(outs + attn)
  gates_h1<<<dim3(2048), blk, 0, stream>>>(outs, attn, aln_g, aln_b, div_w, div_b, h1, gen, cpy);
  // mid = relu(h1 @ fc1^T + b1)
  gemm_ant<<<dim3(64, 32, 1), blk, 0, stream>>>(h1, fc1_w, fc1_b, nullptr, mid,
      2048, 4096, 1024, 1024, 1024, 4096, 0, 0, 0, 1.0f, 1);
  // h2 = mid @ fc2^T + b2
  gemm_ant<<<dim3(16, 32, 1), blk, 0, stream>>>(mid, fc2_w, fc2_b, nullptr, h2,
      2048, 1024, 4096, 4096, 4096, 1024, 0, 0, 0, 1.0f, 0);
  ln_inplace<<<dim3(2048), blk, 0, stream>>>(h2, ffn_g, ffn_b);
  // logits = h2 @ vocab^T  -> d_out
  gemm_ant<<<dim3(500, 32, 1), blk, 0, stream>>>(h2, vocab_w, nullptr, nullptr, out,
      2048, 32000, 1024, 1024, 1024, 32000, 0, 0, 0, 1.0f, 0);
  // softmax over V, * gen_gate, scatter copy probs
  final_scatter<<<dim3(2048), blk, 0, stream>>>(out, w, gen, cpy, copy_seq);
  // log(p + 1e-12) in a separate dispatch (atomic visibility)
  log_k<<<dim3(2048), blk, 0, stream>>>(out, (long)2048 * V_);
}

// Round 3
// 1249.542 us; speedup vs baseline: 4.1902x; 4.1902x over previous
//
#include <hip/hip_runtime.h>
#include <math.h>

#define T_ 256
#define B_ 8
#define S_ 512
#define E_ 1024
#define FF_ 4096
#define V_ 32000
#define LN_EPSF 1e-5f

typedef __attribute__((ext_vector_type(8))) short short8;
typedef __attribute__((ext_vector_type(4))) float f32x4;

// ---------------- block reduction helpers (256 threads = 4 waves) ----------
__device__ __forceinline__ float blkSum(float v, float* sh) {
#pragma unroll
  for (int o = 32; o > 0; o >>= 1) v += __shfl_down(v, o, 64);
  if ((threadIdx.x & 63) == 0) sh[threadIdx.x >> 6] = v;
  __syncthreads();
  float r = sh[0] + sh[1] + sh[2] + sh[3];
  __syncthreads();
  return r;
}
__device__ __forceinline__ float blkMax(float v, float* sh) {
#pragma unroll
  for (int o = 32; o > 0; o >>= 1) v = fmaxf(v, __shfl_down(v, o, 64));
  if ((threadIdx.x & 63) == 0) sh[threadIdx.x >> 6] = v;
  __syncthreads();
  float r = fmaxf(fmaxf(sh[0], sh[1]), fmaxf(sh[2], sh[3]));
  __syncthreads();
  return r;
}

// ---------------- f32 -> bf16 (round to nearest even) -----------------------
__device__ __forceinline__ unsigned short f2bf(float x) {
  unsigned u = __float_as_uint(x);
  u += 0x7FFFu + ((u >> 16) & 1u);
  return (unsigned short)(u >> 16);
}

// ---------------- bf16 MFMA GEMM: C = act((A @ B^T + bias) * scale) ---------
// A: M x K fp32 (row stride lda), B: N x K fp32 (row stride ldb).
// M, N multiples of 128; K multiple of 32. 128x128 tile, BK=32, 256 thr.
// fp32 is converted to bf16 at LDS staging; MFMA 16x16x32, fp32 accum.
// LDS layout [kb][row][8]: fragment ds_read_b128 is bank-uniform.
__global__ __launch_bounds__(256) void gemm_mfma(
    const float* __restrict__ A, const float* __restrict__ Bm,
    const float* __restrict__ bias, float* __restrict__ C,
    int K, int lda, int ldb, int ldc, float scale, int relu)
{
  __shared__ unsigned short sA[4 * 128 * 8];
  __shared__ unsigned short sB[4 * 128 * 8];
  const int row0 = blockIdx.y * 128, col0 = blockIdx.x * 128;
  const float* Ap = A + (long)row0 * lda;
  const float* Bp = Bm + (long)col0 * ldb;

  const int lane = threadIdx.x & 63, wid = threadIdx.x >> 6;
  const int wr = wid >> 1, wc = wid & 1;     // 2x2 waves, each 64x64
  const int lr = lane & 15, kb = lane >> 4;  // frag row/col, k-block

  // staging indices (constant across K-steps)
  const int c0 = threadIdx.x;                 // chunk ids c0 + 256*i
  f32x4 acc[4][4];
#pragma unroll
  for (int mi = 0; mi < 4; ++mi)
#pragma unroll
    for (int ni = 0; ni < 4; ++ni) {
      f32x4 z = {0.f, 0.f, 0.f, 0.f};
      acc[mi][ni] = z;
    }

  for (int k0 = 0; k0 < K; k0 += 32) {
    // ---- stage A and B tiles (fp32 -> bf16) ----
#pragma unroll
    for (int i = 0; i < 4; ++i) {
      int c = c0 + (i << 8);                 // 0..1023
      int kq = c & 7, m = c >> 3;            // 8 float4 per row, 128 rows
      const float4 fa = *(const float4*)(Ap + (long)m * lda + k0 + kq * 4);
      unsigned lo = f2bf(fa.x) | ((unsigned)f2bf(fa.y) << 16);
      unsigned hi = f2bf(fa.z) | ((unsigned)f2bf(fa.w) << 16);
      *(uint2*)&sA[((kq >> 1) * 128 + m) * 8 + (kq & 1) * 4] = make_uint2(lo, hi);
      const float4 fb = *(const float4*)(Bp + (long)m * ldb + k0 + kq * 4);
      lo = f2bf(fb.x) | ((unsigned)f2bf(fb.y) << 16);
      hi = f2bf(fb.z) | ((unsigned)f2bf(fb.w) << 16);
      *(uint2*)&sB[((kq >> 1) * 128 + m) * 8 + (kq & 1) * 4] = make_uint2(lo, hi);
    }
    __syncthreads();
    // ---- fragments + MFMA ----
    short8 af[4], bfr[4];
#pragma unroll
    for (int mi = 0; mi < 4; ++mi)
      af[mi] = *(const short8*)&sA[(kb * 128 + wr * 64 + mi * 16 + lr) * 8];
#pragma unroll
    for (int ni = 0; ni < 4; ++ni)
      bfr[ni] = *(const short8*)&sB[(kb * 128 + wc * 64 + ni * 16 + lr) * 8];
#pragma unroll
    for (int mi = 0; mi < 4; ++mi)
#pragma unroll
      for (int ni = 0; ni < 4; ++ni)
        acc[mi][ni] = __builtin_amdgcn_mfma_f32_16x16x32_bf16(
            af[mi], bfr[ni], acc[mi][ni], 0, 0, 0);
    __syncthreads();
  }

  // ---- epilogue: C/D layout col=lane&15, row=(lane>>4)*4+reg ----
#pragma unroll
  for (int mi = 0; mi < 4; ++mi)
#pragma unroll
    for (int ni = 0; ni < 4; ++ni) {
      int col = col0 + wc * 64 + ni * 16 + lr;
      float bv = bias ? bias[col] : 0.0f;
#pragma unroll
      for (int r = 0; r < 4; ++r) {
        int row = row0 + wr * 64 + mi * 16 + kb * 4 + r;
        float vv = (acc[mi][ni][r] + bv) * scale;
        if (relu) vv = fmaxf(vv, 0.0f);
        C[(long)row * ldc + col] = vv;
      }
    }
}

// ---------------- fp32 batched GEMM (attention scores) ----------------------
__global__ __launch_bounds__(256) void gemm_ant(
    const float* __restrict__ A, const float* __restrict__ Bm,
    const float* __restrict__ bias, const float* __restrict__ sbias,
    float* __restrict__ C, int M, int N, int K,
    int lda, int ldb, int ldc, long aB, long bB, long cB,
    float scale, int relu)
{
  const int bz = blockIdx.z;
  A  += (long)bz * aB;
  Bm += (long)bz * bB;
  C  += (long)bz * cB;
  const float sb = sbias ? sbias[bz] : 0.0f;

  __shared__ float As[64][17];
  __shared__ float Bs[64][17];
  const int tx = threadIdx.x & 15, ty = threadIdx.x >> 4;
  const int row0 = blockIdx.y * 64, col0 = blockIdx.x * 64;

  float acc[4][4] = {};
  for (int k0 = 0; k0 < K; k0 += 16) {
#pragma unroll
    for (int i = 0; i < 4; ++i) {
      int idx = threadIdx.x + 256 * i;
      int r = idx >> 4, c = idx & 15;
      As[r][c] = A[(long)(row0 + r) * lda + k0 + c];
      Bs[r][c] = Bm[(long)(col0 + r) * ldb + k0 + c];
    }
    __syncthreads();
#pragma unroll
    for (int kk = 0; kk < 16; ++kk) {
      float av[4], bv[4];
#pragma unroll
      for (int i = 0; i < 4; ++i) av[i] = As[ty * 4 + i][kk];
#pragma unroll
      for (int j = 0; j < 4; ++j) bv[j] = Bs[tx * 4 + j][kk];
#pragma unroll
      for (int i = 0; i < 4; ++i)
#pragma unroll
        for (int j = 0; j < 4; ++j)
          acc[i][j] = fmaf(av[i], bv[j], acc[i][j]);
    }
    __syncthreads();
  }
#pragma unroll
  for (int i = 0; i < 4; ++i)
#pragma unroll
    for (int j = 0; j < 4; ++j) {
      int m = row0 + ty * 4 + i, n = col0 + tx * 4 + j;
      float v = acc[i][j] + (bias ? bias[n] : 0.0f);
      v = v * scale + sb;
      if (relu) v = fmaxf(v, 0.0f);
      C[(long)m * ldc + n] = v;
    }
}

// ---------------- C = A @ B (B not transposed, batched; attention ctx) ------
__global__ __launch_bounds__(256) void gemm_ab(
    const float* __restrict__ A, const float* __restrict__ Bm,
    float* __restrict__ C, int M, int N, int K,
    int lda, int ldb, int ldc, long aB, long bB, long cB)
{
  const int bz = blockIdx.z;
  A  += (long)bz * aB;
  Bm += (long)bz * bB;
  C  += (long)bz * cB;

  __shared__ float As[64][17];
  __shared__ float Bs[16][65];
  const int tx = threadIdx.x & 15, ty = threadIdx.x >> 4;
  const int row0 = blockIdx.y * 64, col0 = blockIdx.x * 64;

  float acc[4][4] = {};
  for (int k0 = 0; k0 < K; k0 += 16) {
#pragma unroll
    for (int i = 0; i < 4; ++i) {
      int idx = threadIdx.x + 256 * i;
      int r = idx >> 4, c = idx & 15;
      As[r][c] = A[(long)(row0 + r) * lda + k0 + c];
      int rb = idx >> 6, cb = idx & 63;
      Bs[rb][cb] = Bm[(long)(k0 + rb) * ldb + col0 + cb];
    }
    __syncthreads();
#pragma unroll
    for (int kk = 0; kk < 16; ++kk) {
      float av[4], bv[4];
#pragma unroll
      for (int i = 0; i < 4; ++i) av[i] = As[ty * 4 + i][kk];
#pragma unroll
      for (int j = 0; j < 4; ++j) bv[j] = Bs[kk][tx * 4 + j];
#pragma unroll
      for (int i = 0; i < 4; ++i)
#pragma unroll
        for (int j = 0; j < 4; ++j)
          acc[i][j] = fmaf(av[i], bv[j], acc[i][j]);
    }
    __syncthreads();
  }
#pragma unroll
  for (int i = 0; i < 4; ++i)
#pragma unroll
    for (int j = 0; j < 4; ++j)
      C[(long)(row0 + ty * 4 + i) * ldc + col0 + tx * 4 + j] = acc[i][j];
}

// ---------------- masked softmax over s for w[b,t,:] ------------------------
__global__ __launch_bounds__(256) void attn_softmax(
    float* __restrict__ w, const int* __restrict__ mask)
{
  __shared__ float sh[4];
  const int blk = blockIdx.x;          // b*T + t
  const int b = blk / T_;
  float* row = w + (long)blk * S_;
  const int s0 = threadIdx.x, s1 = threadIdx.x + 256;
  const bool k0 = mask[s0 * B_ + b] != 0;
  const bool k1 = mask[s1 * B_ + b] != 0;
  float x0 = k0 ? row[s0] : -INFINITY;
  float x1 = k1 ? row[s1] : -INFINITY;
  float m = blkMax(fmaxf(x0, x1), sh);
  float e0 = k0 ? expf(x0 - m) : 0.0f;
  float e1 = k1 ? expf(x1 - m) : 0.0f;
  float sum = blkSum(e0 + e1, sh);
  float inv = sum > 0.0f ? 1.0f / sum : 0.0f;
  row[s0] = e0 * inv;
  row[s1] = e1 * inv;
}

// ---------------- gates (softmax2 of [outs, LN(attn)] @ div_w^T) + h1 -------
__global__ __launch_bounds__(256) void gates_h1(
    const float* __restrict__ outs, const float* __restrict__ attn,
    const float* __restrict__ aln_g, const float* __restrict__ aln_b,
    const float* __restrict__ div_w, const float* __restrict__ div_b,
    float* __restrict__ h1, float* __restrict__ gen, float* __restrict__ cpy)
{
  __shared__ float sh[4];
  const long base = (long)blockIdx.x * E_;
  float a[4], o[4];
  float sa = 0.f, sa2 = 0.f, shh = 0.f, sh2 = 0.f;
#pragma unroll
  for (int i = 0; i < 4; ++i) {
    int e = threadIdx.x + 256 * i;
    a[i] = attn[base + e];
    o[i] = outs[base + e];
    sa += a[i]; sa2 += a[i] * a[i];
    float t = o[i] + a[i];
    shh += t; sh2 += t * t;
  }
  sa  = blkSum(sa, sh);
  sa2 = blkSum(sa2, sh);
  shh = blkSum(shh, sh);
  sh2 = blkSum(sh2, sh);
  const float ma = sa / E_, va = sa2 / E_ - ma * ma;
  const float mh = shh / E_, vh = sh2 / E_ - mh * mh;
  const float ra = rsqrtf(va + LN_EPSF), rh = rsqrtf(vh + LN_EPSF);

  float z0 = 0.f, z1 = 0.f;
#pragma unroll
  for (int i = 0; i < 4; ++i) {
    int e = threadIdx.x + 256 * i;
    float g = aln_g[e], bb = aln_b[e];
    float an = (a[i] - ma) * ra * g + bb;            // LN(attn)
    float hv = (o[i] + a[i] - mh) * rh * g + bb;     // LN(outs+attn)
    h1[base + e] = hv;
    z0 += o[i] * div_w[e]          + an * div_w[E_ + e];
    z1 += o[i] * div_w[2 * E_ + e] + an * div_w[3 * E_ + e];
  }
  z0 = blkSum(z0, sh);
  z1 = blkSum(z1, sh);
  if (threadIdx.x == 0) {
    z0 += div_b[0]; z1 += div_b[1];
    float mm = fmaxf(z0, z1);
    float e0 = expf(z0 - mm), e1 = expf(z1 - mm);
    float inv = 1.0f / (e0 + e1);
    gen[blockIdx.x] = e0 * inv;
    cpy[blockIdx.x] = e1 * inv;
  }
}

// ---------------- in-place LayerNorm over last dim E ------------------------
__global__ __launch_bounds__(256) void ln_inplace(
    float* __restrict__ x, const float* __restrict__ g, const float* __restrict__ b)
{
  __shared__ float sh[4];
  const long base = (long)blockIdx.x * E_;
  float v[4];
  float s = 0.f, s2 = 0.f;
#pragma unroll
  for (int i = 0; i < 4; ++i) {
    v[i] = x[base + threadIdx.x + 256 * i];
    s += v[i]; s2 += v[i] * v[i];
  }
  s  = blkSum(s, sh);
  s2 = blkSum(s2, sh);
  const float m = s / E_, var = s2 / E_ - m * m;
  const float r = rsqrtf(var + LN_EPSF);
#pragma unroll
  for (int i = 0; i < 4; ++i) {
    int e = threadIdx.x + 256 * i;
    x[base + e] = (v[i] - m) * r * g[e] + b[e];
  }
}

// ---------------- per-row: softmax(V) * gen + scatter(copy) -----------------
// online (max,sum) in one read pass, then exp-write pass, then scatter.
__global__ __launch_bounds__(256) void final_scatter(
    float* __restrict__ out,              // (T*B, V): logits in, probs out
    const float* __restrict__ w,          // (B,T,S) post-softmax
    const float* __restrict__ gen, const float* __restrict__ cpy,
    const int* __restrict__ copy_seq)     // (S,B)
{
  __shared__ float sh[4];
  const int r = blockIdx.x;               // t*B + b
  const int t = r / B_, b = r % B_;
  float* row = out + (long)r * V_;

  float mx = -INFINITY, s = 0.f;
  for (int v = threadIdx.x; v < V_; v += 256) {
    float x = row[v];
    if (x > mx) { s *= expf(mx - x); mx = x; }
    s += expf(x - mx);
  }
  float gmx = blkMax(mx, sh);
  s = blkSum(s * expf(mx - gmx), sh);

  const float scale = gen[r] / s;
  for (int v = threadIdx.x; v < V_; v += 256) row[v] = expf(row[v] - gmx) * scale;
  __syncthreads();

  const float cg = cpy[r];
  const float* wrow = w + ((long)b * T_ + t) * S_;
  for (int sdx = threadIdx.x; sdx < S_; sdx += 256)
    atomicAdd(&row[copy_seq[sdx * B_ + b]], cg * wrow[sdx]);
}

// ---------------- elementwise log(p + 1e-12), separate dispatch -------------
__global__ __launch_bounds__(256) void log_k(float* __restrict__ out, long n)
{
  long i = (long)blockIdx.x * 256 + threadIdx.x;
  long stride = (long)gridDim.x * 256;
  for (; i < n; i += stride) out[i] = logf(out[i] + 1e-12f);
}

// ---------------- launch ----------------------------------------------------
extern "C" void kernel_launch(void* const* d_in, const int* in_sizes, int n_in,
                              void* d_out, int out_size, void* d_ws, size_t ws_size,
                              hipStream_t stream) {
  (void)in_sizes; (void)n_in; (void)out_size; (void)ws_size;
  const float* outs     = (const float*)d_in[0];
  const float* mem      = (const float*)d_in[1];
  const float* mem_bias = (const float*)d_in[2];
  const float* in_w     = (const float*)d_in[3];
  const float* in_b     = (const float*)d_in[4];
  const float* ow       = (const float*)d_in[5];
  const float* ob       = (const float*)d_in[6];
  const float* aln_g    = (const float*)d_in[7];
  const float* aln_b    = (const float*)d_in[8];
  const float* div_w    = (const float*)d_in[9];
  const float* div_b    = (const float*)d_in[10];
  const float* fc1_w    = (const float*)d_in[11];
  const float* fc1_b    = (const float*)d_in[12];
  const float* fc2_w    = (const float*)d_in[13];
  const float* fc2_b    = (const float*)d_in[14];
  const float* ffn_g    = (const float*)d_in[15];
  const float* ffn_b    = (const float*)d_in[16];
  const float* vocab_w  = (const float*)d_in[17];
  const int*   mask     = (const int*)d_in[18];
  const int*   copy_seq = (const int*)d_in[19];
  float* out = (float*)d_out;
  float* ws  = (float*)d_ws;

  // workspace layout (floats) — identical to the passing round:
  // ctx reuses q, h1 reuses v, h2 reuses k, FFN mid lives in d_out.
  float* k    = ws;                   // 4096*1024
  float* v    = ws + 4194304;         // 4096*1024
  float* q    = ws + 8388608;         // 2048*1024
  float* w    = ws + 10485760;        // 8*256*512
  float* attn = ws + 11534336;        // 2048*1024
  float* gen  = ws + 13631488;        // 2048
  float* cpy  = gen + 2048;           // 2048
  float* ctx  = q;
  float* h1   = v;
  float* h2   = k;
  float* mid  = out;

  dim3 blk(256);
  // q = (outs @ Wq^T + bq) * E^-0.5        grid (N/128, M/128)
  gemm_mfma<<<dim3(8, 16), blk, 0, stream>>>(outs, in_w, in_b, q,
      1024, 1024, 1024, 1024, 0.03125f, 0);
  // k = mem @ Wk^T + bk
  gemm_mfma<<<dim3(8, 32), blk, 0, stream>>>(mem, in_w + E_ * E_, in_b + E_, k,
      1024, 1024, 1024, 1024, 1.0f, 0);
  // v = mem @ Wv^T + bv
  gemm_mfma<<<dim3(8, 32), blk, 0, stream>>>(mem, in_w + 2 * E_ * E_, in_b + 2 * E_, v,
      1024, 1024, 1024, 1024, 1.0f, 0);
  // w[b,t,s] = q[t,b,:] . k[s,b,:] + mem_bias[b]   (batched over b, fp32)
  gemm_ant<<<dim3(8, 4, 8), blk, 0, stream>>>(q, k, nullptr, mem_bias, w,
      256, 512, 1024, B_ * E_, B_ * E_, S_, E_, E_, (long)T_ * S_, 1.0f, 0);
  attn_softmax<<<dim3(B_ * T_), blk, 0, stream>>>(w, mask);
  // ctx[t,b,:] = sum_s w[b,t,s] * v[s,b,:]  (batched, fp32)
  gemm_ab<<<dim3(16, 4, 8), blk, 0, stream>>>(w, v, ctx,
      256, 1024, 512, S_, B_ * E_, B_ * E_, (long)T_ * S_, E_, E_);
  // attn = ctx @ Wo^T + bo
  gemm_mfma<<<dim3(8, 16), blk, 0, stream>>>(ctx, ow, ob, attn,
      1024, 1024, 1024, 1024, 1.0f, 0);
  // gates + h1 = LN(outs + attn)
  gates_h1<<<dim3(2048), blk, 0, stream>>>(outs, attn, aln_g, aln_b, div_w, div_b, h1, gen, cpy);
  // mid = relu(h1 @ fc1^T + b1)
  gemm_mfma<<<dim3(32, 16), blk, 0, stream>>>(h1, fc1_w, fc1_b, mid,
      1024, 1024, 1024, 4096, 1.0f, 1);
  // h2 = mid @ fc2^T + b2
  gemm_mfma<<<dim3(8, 16), blk, 0, stream>>>(mid, fc2_w, fc2_b, h2,
      4096, 4096, 4096, 1024, 1.0f, 0);
  ln_inplace<<<dim3(2048), blk, 0, stream>>>(h2, ffn_g, ffn_b);
  // logits = h2 @ vocab^T  -> d_out
  gemm_mfma<<<dim3(250, 16), blk, 0, stream>>>(h2, vocab_w, nullptr, out,
      1024, 1024, 1024, 32000, 1.0f, 0);
  // softmax over V, * gen_gate, scatter copy probs
  final_scatter<<<dim3(2048), blk, 0, stream>>>(out, w, gen, cpy, copy_seq);
  // log(p + 1e-12) in a separate dispatch (atomic visibility)
  log_k<<<dim3(2048), blk, 0, stream>>>(out, (long)2048 * V_);
}